// Round 6
// baseline (179.503 us; speedup 1.0000x reference)
//
#include <hip/hip_runtime.h>
#include <hip/hip_bf16.h>

// Problem constants
#define NB    8
#define CCH   64      // CIN = COUT = 64
#define HH    128
#define WW    128
#define KTAP  9
#define HW    (HH * WW)            // 16384
#define KSTEPS 18                  // 576 / 32
#define NW    36864                // weight elements

typedef _Float16 f16x8 __attribute__((ext_vector_type(8)));
typedef _Float16 f16x2 __attribute__((ext_vector_type(2)));
typedef __attribute__((ext_vector_type(4))) float f32x4;

// RNE f32 pair -> packed f16x2 (as uint)
__device__ inline unsigned int pack_f16(float a, float b) {
    f16x2 h;
    h[0] = (_Float16)a;   // v_cvt_f16_f32 (RNE)
    h[1] = (_Float16)b;
    return __builtin_bit_cast(unsigned int, h);
}

__device__ inline f16x8 as_f16x8(uint4 u) { return __builtin_bit_cast(f16x8, u); }

// ---------- K1: transpose x NCHW f32 -> xt NHWC f16 (blocks 0..2047)
//             + weight quant into MFMA B frags (blocks 2048..2065, redundant maxabs)
__global__ __launch_bounds__(256) void prep_kernel(const float* __restrict__ x,
                                                   const float* __restrict__ w,
                                                   unsigned int* __restrict__ xt32,
                                                   uint4* __restrict__ bq) {
    __shared__ float tile[64 * 65];
    const int t = threadIdx.x;
    const int bid = blockIdx.x;

    if (bid < 2048) {
        // ---- transpose 64 channels x 64 pixels ----
        const int n = bid >> 8;
        const int pbase = (bid & 255) * 64;
        #pragma unroll
        for (int i = 0; i < 4; i++) {
            int idx = i * 256 + t;
            int c = idx >> 4, f4 = idx & 15;
            float4 v = *(const float4*)&x[((size_t)(n * CCH + c)) * HW + pbase + f4 * 4];
            float* d = &tile[c * 65 + f4 * 4];
            d[0] = v.x; d[1] = v.y; d[2] = v.z; d[3] = v.w;
        }
        __syncthreads();
        const int px = t >> 2, c4 = t & 3;
        float f[16];
        #pragma unroll
        for (int j = 0; j < 16; j++) f[j] = tile[(c4 * 16 + j) * 65 + px];
        unsigned int o8[8];
        #pragma unroll
        for (int i = 0; i < 8; i++) o8[i] = pack_f16(f[2 * i], f[2 * i + 1]);
        uint4* dst = (uint4*)&xt32[((size_t)(n * HW + pbase + px)) * 32 + c4 * 8];
        dst[0] = make_uint4(o8[0], o8[1], o8[2], o8[3]);
        dst[1] = make_uint4(o8[4], o8[5], o8[6], o8[7]);
    } else {
        // ---- each of 18 blocks: full maxabs (parallel, redundant) + 256 recs ----
        float m0 = 0.f, m1 = 0.f, m2 = 0.f, m3 = 0.f;
        for (int i = t; i < NW; i += 1024) {       // 36 iters, 4-way ILP
            m0 = fmaxf(m0, fabsf(w[i]));
            m1 = fmaxf(m1, fabsf(w[i + 256]));
            m2 = fmaxf(m2, fabsf(w[i + 512]));
            m3 = fmaxf(m3, fabsf(w[i + 768]));
        }
        float m = fmaxf(fmaxf(m0, m1), fmaxf(m2, m3));
        #pragma unroll
        for (int off = 32; off > 0; off >>= 1)
            m = fmaxf(m, __shfl_down(m, off));
        if ((t & 63) == 0) tile[t >> 6] = m;
        __syncthreads();
        m = fmaxf(fmaxf(tile[0], tile[1]), fmaxf(tile[2], tile[3]));
        const float scale = fmaxf(m, 1e-8f) / 127.f;
        const float inv_scale = 1.f / scale;

        const int rec = (bid - 2048) * 256 + t;    // 0..4607
        int nt  = rec / (KSTEPS * 64);
        int rem = rec - nt * (KSTEPS * 64);
        int s    = rem >> 6;
        int lane = rem & 63;
        int quad = lane >> 4, n16 = lane & 15;
        int o = nt * 16 + n16;
        unsigned int u[4];
        #pragma unroll
        for (int jj = 0; jj < 4; jj++) {
            float q[2];
            #pragma unroll
            for (int h = 0; h < 2; h++) {
                int k   = s * 32 + quad * 8 + 2 * jj + h;
                int c   = k & 63;
                int tap = k >> 6;
                float v  = w[(o * CCH + c) * KTAP + tap];
                float qq = rintf(v * inv_scale);          // RNE = jnp.round
                q[h] = fminf(fmaxf(qq, -128.f), 127.f) * scale;
            }
            u[jj] = pack_f16(q[0], q[1]);
        }
        bq[rec] = make_uint4(u[0], u[1], u[2], u[3]);
    }
}

// ---------- K2: fused deformable-sample + MFMA GEMM, barrier-free tap loop ----------
// Block = 64 pixels x 64 outs; wave w owns pixels [w*16, w*16+16) x ALL 64 outs.
// A-fragment built directly in registers: lane gathers pixel (lane&15),
// channels quad*8..+8 -> exactly the 16x16x32 A layout. No LDS A-tile.
__global__ __launch_bounds__(256) void deform_mfma(const unsigned short* __restrict__ xt,
                                                   const float* __restrict__ offset,
                                                   const uint4* __restrict__ bq,
                                                   float* __restrict__ out) {
    __shared__ unsigned int SC[576];       // packed clamped corners per (tap,px)
    __shared__ uint2 SW[576];              // packed f16 bilinear weights

    const int t    = threadIdx.x;
    const int wid  = t >> 6;
    const int lane = t & 63;
    const int quad = lane >> 4, n16 = lane & 15;
    const int bid  = blockIdx.x;
    const int n    = bid & 7;                 // image -> XCD swizzle
    const int px0  = (bid >> 3) * 64;
    const int mypix = wid * 16 + n16;         // this lane's pixel within block

    const char* xb = (const char*)(xt + (size_t)n * HW * CCH);
    const float* offn = offset + (size_t)n * 2 * KTAP * HW;

    // ---- setup: one task per (tap, pixel), cooperative across 256 threads ----
    for (int u = t; u < 576; u += 256) {
        const int tap = u >> 6, p = u & 63;
        const int ppx = px0 + p;
        const int ho = ppx >> 7, wo = ppx & 127;
        const int ky = tap / 3, kx = tap - 3 * ky;
        const float py  = (float)(ho - 1 + ky) + offn[(2 * tap) * HW + ppx];
        const float pxf = (float)(wo - 1 + kx) + offn[(2 * tap + 1) * HW + ppx];
        const float fy = floorf(py), fx = floorf(pxf);
        const int y0 = (int)fy, x0 = (int)fx;
        const float dy = py - fy, dx = pxf - fx;
        const int y1 = y0 + 1, x1 = x0 + 1;
        const bool vy0 = (y0 >= 0) && (y0 < HH);
        const bool vy1 = (y1 >= 0) && (y1 < HH);
        const bool vx0 = (x0 >= 0) && (x0 < WW);
        const bool vx1 = (x1 >= 0) && (x1 < WW);
        const int y0c = min(max(y0, 0), HH - 1);
        const int y1c = min(max(y1, 0), HH - 1);
        const int x0c = min(max(x0, 0), WW - 1);
        const int x1c = min(max(x1, 0), WW - 1);
        const float w00 = (1.f - dy) * (1.f - dx) * ((vy0 && vx0) ? 1.f : 0.f);
        const float w01 = (1.f - dy) * dx         * ((vy0 && vx1) ? 1.f : 0.f);
        const float w10 = dy * (1.f - dx)         * ((vy1 && vx0) ? 1.f : 0.f);
        const float w11 = dy * dx                 * ((vy1 && vx1) ? 1.f : 0.f);
        SC[u] = (unsigned)(y0c | (x0c << 7) | (y1c << 14) | (x1c << 21));
        SW[u] = make_uint2(pack_f16(w00, w01), pack_f16(w10, w11));
    }
    __syncthreads();           // the ONLY barrier

    f32x4 acc[4];
    #pragma unroll
    for (int nt = 0; nt < 4; nt++) acc[nt] = (f32x4){0.f, 0.f, 0.f, 0.f};

    const int cb = quad * 16;  // A chunk byte offset: slice0 = quad*16, slice1 = +64

    #pragma unroll 1
    for (int tap = 0; tap < KTAP; tap++) {
        // Gathers first (blend's wait then leaves B loads outstanding longer)
        const unsigned int cc = SC[tap * 64 + mypix];
        const int y0b = (int)(cc & 127) << 14;
        const int x0b = (int)((cc >> 7) & 127) << 7;
        const int y1b = (int)((cc >> 14) & 127) << 14;
        const int x1b = (int)(cc >> 21) << 7;
        const char* q00 = xb + (y0b | x0b) + cb;
        const char* q01 = xb + (y0b | x1b) + cb;
        const char* q10 = xb + (y1b | x0b) + cb;
        const char* q11 = xb + (y1b | x1b) + cb;
        uint4 r0 = *(const uint4*)q00, r1 = *(const uint4*)(q00 + 64);
        uint4 r2 = *(const uint4*)q01, r3 = *(const uint4*)(q01 + 64);
        uint4 r4 = *(const uint4*)q10, r5 = *(const uint4*)(q10 + 64);
        uint4 r6 = *(const uint4*)q11, r7 = *(const uint4*)(q11 + 64);

        // B fragments: 4 out-slabs x 2 K-slices (L1-resident, coalesced)
        uint4 bf[8];
        #pragma unroll
        for (int nt = 0; nt < 4; nt++) {
            bf[nt * 2 + 0] = bq[((nt * KSTEPS) + tap * 2 + 0) * 64 + lane];
            bf[nt * 2 + 1] = bq[((nt * KSTEPS) + tap * 2 + 1) * 64 + lane];
        }

        const uint2 ww = SW[tap * 64 + mypix];
        const f16x2 wA = __builtin_bit_cast(f16x2, ww.x);   // w00, w01
        const f16x2 wB = __builtin_bit_cast(f16x2, ww.y);   // w10, w11
        f16x8 sa = as_f16x8(r0) * wA[0];
        sa += as_f16x8(r2) * wA[1];
        sa += as_f16x8(r4) * wB[0];
        sa += as_f16x8(r6) * wB[1];
        f16x8 sb = as_f16x8(r1) * wA[0];
        sb += as_f16x8(r3) * wA[1];
        sb += as_f16x8(r5) * wB[0];
        sb += as_f16x8(r7) * wB[1];

        #pragma unroll
        for (int nt = 0; nt < 4; nt++) {
            acc[nt] = __builtin_amdgcn_mfma_f32_16x16x32_f16(
                sa, __builtin_bit_cast(f16x8, bf[nt * 2 + 0]), acc[nt], 0, 0, 0);
            acc[nt] = __builtin_amdgcn_mfma_f32_16x16x32_f16(
                sb, __builtin_bit_cast(f16x8, bf[nt * 2 + 1]), acc[nt], 0, 0, 0);
        }
    }

    // Epilogue: D row = quad*4+reg (pixel), col = n16 (out channel within slab)
    #pragma unroll
    for (int nt = 0; nt < 4; nt++) {
        const int o = nt * 16 + n16;
        float4 v = make_float4(acc[nt].x, acc[nt].y, acc[nt].z, acc[nt].w);
        float* dst = out + ((size_t)(n * CCH + o)) * HW + px0 + wid * 16 + quad * 4;
        *(float4*)dst = v;   // 4 consecutive pixels, same out channel
    }
}

extern "C" void kernel_launch(void* const* d_in, const int* in_sizes, int n_in,
                              void* d_out, int out_size, void* d_ws, size_t ws_size,
                              hipStream_t stream) {
    const float* x      = (const float*)d_in[0];   // [8,64,128,128]
    const float* offset = (const float*)d_in[1];   // [8,18,128,128]
    const float* weight = (const float*)d_in[2];   // [64,64,3,3]
    float* out = (float*)d_out;                    // [8,64,128,128]

    unsigned char* ws = (unsigned char*)d_ws;
    uint4*        bq   = (uint4*)ws;                        // 73728 B
    unsigned int* xt32 = (unsigned int*)(ws + 131072);      // 8 MB (f16 NHWC)
    const unsigned short* xt = (const unsigned short*)xt32;

    prep_kernel<<<2048 + 18, 256, 0, stream>>>(x, weight, xt32, bq);
    deform_mfma<<<2048, 256, 0, stream>>>(xt, offset, bq, out);
}

// Round 7
// 173.988 us; speedup vs baseline: 1.0317x; 1.0317x over previous
//
#include <hip/hip_runtime.h>
#include <hip/hip_bf16.h>

// Problem constants
#define NB    8
#define CCH   64      // CIN = COUT = 64
#define HH    128
#define WW    128
#define KTAP  9
#define HW    (HH * WW)            // 16384
#define KSTEPS 18                  // 576 / 32
#define NW    36864                // weight elements
#define LDSTAPS 7                  // taps 0..6 B-frags staged in LDS

typedef _Float16 f16x8 __attribute__((ext_vector_type(8)));
typedef _Float16 f16x2 __attribute__((ext_vector_type(2)));
typedef __attribute__((ext_vector_type(4))) float f32x4;

// RNE f32 pair -> packed f16x2 (as uint)
__device__ inline unsigned int pack_f16(float a, float b) {
    f16x2 h;
    h[0] = (_Float16)a;   // v_cvt_f16_f32 (RNE)
    h[1] = (_Float16)b;
    return __builtin_bit_cast(unsigned int, h);
}

__device__ inline f16x8 as_f16x8(uint4 u) { return __builtin_bit_cast(f16x8, u); }

// ---------- K1: transpose x NCHW f32 -> xt NHWC f16 (blocks 0..2047)
//             + weight quant into MFMA B frags (blocks 2048..2065, redundant maxabs)
__global__ __launch_bounds__(256) void prep_kernel(const float* __restrict__ x,
                                                   const float* __restrict__ w,
                                                   unsigned int* __restrict__ xt32,
                                                   uint4* __restrict__ bq) {
    __shared__ float tile[64 * 65];
    const int t = threadIdx.x;
    const int bid = blockIdx.x;

    if (bid < 2048) {
        // ---- transpose 64 channels x 64 pixels ----
        const int n = bid >> 8;
        const int pbase = (bid & 255) * 64;
        #pragma unroll
        for (int i = 0; i < 4; i++) {
            int idx = i * 256 + t;
            int c = idx >> 4, f4 = idx & 15;
            float4 v = *(const float4*)&x[((size_t)(n * CCH + c)) * HW + pbase + f4 * 4];
            float* d = &tile[c * 65 + f4 * 4];
            d[0] = v.x; d[1] = v.y; d[2] = v.z; d[3] = v.w;
        }
        __syncthreads();
        const int px = t >> 2, c4 = t & 3;
        float f[16];
        #pragma unroll
        for (int j = 0; j < 16; j++) f[j] = tile[(c4 * 16 + j) * 65 + px];
        unsigned int o8[8];
        #pragma unroll
        for (int i = 0; i < 8; i++) o8[i] = pack_f16(f[2 * i], f[2 * i + 1]);
        uint4* dst = (uint4*)&xt32[((size_t)(n * HW + pbase + px)) * 32 + c4 * 8];
        dst[0] = make_uint4(o8[0], o8[1], o8[2], o8[3]);
        dst[1] = make_uint4(o8[4], o8[5], o8[6], o8[7]);
    } else {
        // ---- each of 18 blocks: full maxabs (parallel, redundant) + 256 recs ----
        float m0 = 0.f, m1 = 0.f, m2 = 0.f, m3 = 0.f;
        for (int i = t; i < NW; i += 1024) {       // 36 iters, 4-way ILP
            m0 = fmaxf(m0, fabsf(w[i]));
            m1 = fmaxf(m1, fabsf(w[i + 256]));
            m2 = fmaxf(m2, fabsf(w[i + 512]));
            m3 = fmaxf(m3, fabsf(w[i + 768]));
        }
        float m = fmaxf(fmaxf(m0, m1), fmaxf(m2, m3));
        #pragma unroll
        for (int off = 32; off > 0; off >>= 1)
            m = fmaxf(m, __shfl_down(m, off));
        if ((t & 63) == 0) tile[t >> 6] = m;
        __syncthreads();
        m = fmaxf(fmaxf(tile[0], tile[1]), fmaxf(tile[2], tile[3]));
        const float scale = fmaxf(m, 1e-8f) / 127.f;
        const float inv_scale = 1.f / scale;

        const int rec = (bid - 2048) * 256 + t;    // 0..4607
        int nt  = rec / (KSTEPS * 64);
        int rem = rec - nt * (KSTEPS * 64);
        int s    = rem >> 6;
        int lane = rem & 63;
        int quad = lane >> 4, n16 = lane & 15;
        int o = nt * 16 + n16;
        unsigned int u[4];
        #pragma unroll
        for (int jj = 0; jj < 4; jj++) {
            float q[2];
            #pragma unroll
            for (int h = 0; h < 2; h++) {
                int k   = s * 32 + quad * 8 + 2 * jj + h;
                int c   = k & 63;
                int tap = k >> 6;
                float v  = w[(o * CCH + c) * KTAP + tap];
                float qq = rintf(v * inv_scale);          // RNE = jnp.round
                q[h] = fminf(fmaxf(qq, -128.f), 127.f) * scale;
            }
            u[jj] = pack_f16(q[0], q[1]);
        }
        bq[rec] = make_uint4(u[0], u[1], u[2], u[3]);
    }
}

// ---------- K2: deformable-sample + MFMA, register-direct A, LDS-staged B ----------
// Block = 64 px x 64 outs; wave w owns pixels [w*16, +16) x ALL 64 outs.
// Lane gathers pixel (lane&15), channel bytes quad*16 (+64) -> exact A-frag layout.
// B taps 0..6 staged in LDS (one barrier, merged with setup); taps 7,8 via VMEM.
// Fully unrolled tap loop with manual double-buffered prefetch (1-tap distance).
__global__ __launch_bounds__(256, 2) void deform_mfma(const unsigned short* __restrict__ xt,
                                                      const float* __restrict__ offset,
                                                      const uint4* __restrict__ bq,
                                                      float* __restrict__ out) {
    __shared__ uint4 Blds[4 * LDSTAPS * 2 * 64];   // 57344 B: [(nt*7+tap)*2+sl][lane]
    __shared__ unsigned int SC[576];               // 2304 B: packed clamped corners
    __shared__ uint2 SW[576];                      // 4608 B: packed f16 bilinear wts

    const int t    = threadIdx.x;
    const int wid  = t >> 6;
    const int lane = t & 63;
    const int quad = lane >> 4, n16 = lane & 15;
    const int bid  = blockIdx.x;
    const int n    = bid & 7;                 // image -> XCD swizzle
    const int px0  = (bid >> 3) * 64;
    const int mypix = wid * 16 + n16;         // this lane's pixel within block

    const char* xb = (const char*)(xt + (size_t)n * HW * CCH);
    const float* offn = offset + (size_t)n * 2 * KTAP * HW;

    // ---- stage B taps 0..6 into LDS: 3584 uint4, coalesced, 14 per thread ----
    #pragma unroll
    for (int k = 0; k < 14; k++) {
        const int i = k * 256 + t;            // flat uint4 index in Blds
        const int rl = i >> 6;                // 0..55
        const int ln = i & 63;
        const int nt = rl / 14;
        const int s  = rl - nt * 14;          // kstep 0..13 (taps 0..6)
        Blds[i] = bq[(nt * KSTEPS + s) * 64 + ln];
    }

    // ---- setup: one task per (tap, pixel), cooperative across 256 threads ----
    for (int u = t; u < 576; u += 256) {
        const int tap = u >> 6, p = u & 63;
        const int ppx = px0 + p;
        const int ho = ppx >> 7, wo = ppx & 127;
        const int ky = tap / 3, kx = tap - 3 * ky;
        const float py  = (float)(ho - 1 + ky) + offn[(2 * tap) * HW + ppx];
        const float pxf = (float)(wo - 1 + kx) + offn[(2 * tap + 1) * HW + ppx];
        const float fy = floorf(py), fx = floorf(pxf);
        const int y0 = (int)fy, x0 = (int)fx;
        const float dy = py - fy, dx = pxf - fx;
        const int y1 = y0 + 1, x1 = x0 + 1;
        const bool vy0 = (y0 >= 0) && (y0 < HH);
        const bool vy1 = (y1 >= 0) && (y1 < HH);
        const bool vx0 = (x0 >= 0) && (x0 < WW);
        const bool vx1 = (x1 >= 0) && (x1 < WW);
        const int y0c = min(max(y0, 0), HH - 1);
        const int y1c = min(max(y1, 0), HH - 1);
        const int x0c = min(max(x0, 0), WW - 1);
        const int x1c = min(max(x1, 0), WW - 1);
        const float w00 = (1.f - dy) * (1.f - dx) * ((vy0 && vx0) ? 1.f : 0.f);
        const float w01 = (1.f - dy) * dx         * ((vy0 && vx1) ? 1.f : 0.f);
        const float w10 = dy * (1.f - dx)         * ((vy1 && vx0) ? 1.f : 0.f);
        const float w11 = dy * dx                 * ((vy1 && vx1) ? 1.f : 0.f);
        SC[u] = (unsigned)(y0c | (x0c << 7) | (y1c << 14) | (x1c << 21));
        SW[u] = make_uint2(pack_f16(w00, w01), pack_f16(w10, w11));
    }
    __syncthreads();           // the ONLY barrier

    f32x4 acc[4];
    #pragma unroll
    for (int nt = 0; nt < 4; nt++) acc[nt] = (f32x4){0.f, 0.f, 0.f, 0.f};

    const int cb = quad * 16;  // A chunk byte offset within 128B pixel row

    uint4 rset[2][8];          // double-buffered gather data
    uint4 bset[2][8];          // double-buffered B fragments
    uint2 wset[2];             // bilinear weights for buffered tap

    auto issue = [&](int tap, int b) {
        // gathers
        const unsigned int cc = SC[tap * 64 + mypix];
        wset[b] = SW[tap * 64 + mypix];
        const int y0b = (int)(cc & 127) << 14;
        const int x0b = (int)((cc >> 7) & 127) << 7;
        const int y1b = (int)((cc >> 14) & 127) << 14;
        const int x1b = (int)(cc >> 21) << 7;
        const char* q00 = xb + (y0b | x0b) + cb;
        const char* q01 = xb + (y0b | x1b) + cb;
        const char* q10 = xb + (y1b | x0b) + cb;
        const char* q11 = xb + (y1b | x1b) + cb;
        rset[b][0] = *(const uint4*)q00; rset[b][1] = *(const uint4*)(q00 + 64);
        rset[b][2] = *(const uint4*)q01; rset[b][3] = *(const uint4*)(q01 + 64);
        rset[b][4] = *(const uint4*)q10; rset[b][5] = *(const uint4*)(q10 + 64);
        rset[b][6] = *(const uint4*)q11; rset[b][7] = *(const uint4*)(q11 + 64);
        // B fragments: LDS for taps 0..6, global (L2-hit) for taps 7,8
        if (tap < LDSTAPS) {
            #pragma unroll
            for (int nt = 0; nt < 4; nt++) {
                bset[b][nt * 2 + 0] = Blds[((nt * LDSTAPS + tap) * 2 + 0) * 64 + lane];
                bset[b][nt * 2 + 1] = Blds[((nt * LDSTAPS + tap) * 2 + 1) * 64 + lane];
            }
        } else {
            #pragma unroll
            for (int nt = 0; nt < 4; nt++) {
                bset[b][nt * 2 + 0] = bq[(nt * KSTEPS + tap * 2 + 0) * 64 + lane];
                bset[b][nt * 2 + 1] = bq[(nt * KSTEPS + tap * 2 + 1) * 64 + lane];
            }
        }
    };

    auto consume = [&](int b) {
        const f16x2 wA = __builtin_bit_cast(f16x2, wset[b].x);   // w00, w01
        const f16x2 wB = __builtin_bit_cast(f16x2, wset[b].y);   // w10, w11
        f16x8 sa = as_f16x8(rset[b][0]) * wA[0];
        sa += as_f16x8(rset[b][2]) * wA[1];
        sa += as_f16x8(rset[b][4]) * wB[0];
        sa += as_f16x8(rset[b][6]) * wB[1];
        f16x8 sb = as_f16x8(rset[b][1]) * wA[0];
        sb += as_f16x8(rset[b][3]) * wA[1];
        sb += as_f16x8(rset[b][5]) * wB[0];
        sb += as_f16x8(rset[b][7]) * wB[1];
        #pragma unroll
        for (int nt = 0; nt < 4; nt++) {
            acc[nt] = __builtin_amdgcn_mfma_f32_16x16x32_f16(
                sa, __builtin_bit_cast(f16x8, bset[b][nt * 2 + 0]), acc[nt], 0, 0, 0);
            acc[nt] = __builtin_amdgcn_mfma_f32_16x16x32_f16(
                sb, __builtin_bit_cast(f16x8, bset[b][nt * 2 + 1]), acc[nt], 0, 0, 0);
        }
    };

    issue(0, 0);
    #pragma unroll
    for (int tap = 0; tap < KTAP; tap++) {
        if (tap < KTAP - 1) issue(tap + 1, (tap + 1) & 1);  // full-tap prefetch distance
        consume(tap & 1);
    }

    // Epilogue: D row = quad*4+reg (pixel), col = n16 (out channel within slab)
    #pragma unroll
    for (int nt = 0; nt < 4; nt++) {
        const int o = nt * 16 + n16;
        float4 v = make_float4(acc[nt].x, acc[nt].y, acc[nt].z, acc[nt].w);
        float* dst = out + ((size_t)(n * CCH + o)) * HW + px0 + wid * 16 + quad * 4;
        *(float4*)dst = v;   // 4 consecutive pixels, same out channel
    }
}

extern "C" void kernel_launch(void* const* d_in, const int* in_sizes, int n_in,
                              void* d_out, int out_size, void* d_ws, size_t ws_size,
                              hipStream_t stream) {
    const float* x      = (const float*)d_in[0];   // [8,64,128,128]
    const float* offset = (const float*)d_in[1];   // [8,18,128,128]
    const float* weight = (const float*)d_in[2];   // [64,64,3,3]
    float* out = (float*)d_out;                    // [8,64,128,128]

    unsigned char* ws = (unsigned char*)d_ws;
    uint4*        bq   = (uint4*)ws;                        // 73728 B
    unsigned int* xt32 = (unsigned int*)(ws + 131072);      // 8 MB (f16 NHWC)
    const unsigned short* xt = (const unsigned short*)xt32;

    prep_kernel<<<2048 + 18, 256, 0, stream>>>(x, weight, xt32, bq);
    deform_mfma<<<2048, 256, 0, stream>>>(xt, offset, bq, out);
}

// Round 9
// 131.107 us; speedup vs baseline: 1.3691x; 1.3271x over previous
//
#include <hip/hip_runtime.h>
#include <hip/hip_bf16.h>

// Problem constants
#define NB    8
#define CCH   64      // CIN = COUT = 64
#define HH    128
#define WW    128
#define KTAP  9
#define HW    (HH * WW)            // 16384
#define KSTEPS 18                  // 576 / 32
#define NW    36864                // weight elements

typedef _Float16 f16x8 __attribute__((ext_vector_type(8)));
typedef _Float16 f16x2 __attribute__((ext_vector_type(2)));
typedef __attribute__((ext_vector_type(4))) float f32x4;

// RNE f32 pair -> packed f16x2 (as uint)
__device__ inline unsigned int pack_f16(float a, float b) {
    f16x2 h;
    h[0] = (_Float16)a;   // v_cvt_f16_f32 (RNE)
    h[1] = (_Float16)b;
    return __builtin_bit_cast(unsigned int, h);
}

__device__ inline f16x8 as_f16x8(uint4 u) { return __builtin_bit_cast(f16x8, u); }

// ---------- K1: transpose x NCHW f32 -> xt NHWC f16 (blocks 0..2047)
//             + weight quant into MFMA B frags (blocks 2048..2065, redundant maxabs)
__global__ __launch_bounds__(256) void prep_kernel(const float* __restrict__ x,
                                                   const float* __restrict__ w,
                                                   unsigned int* __restrict__ xt32,
                                                   uint4* __restrict__ bq) {
    __shared__ float tile[64 * 65];
    const int t = threadIdx.x;
    const int bid = blockIdx.x;

    if (bid < 2048) {
        // ---- transpose 64 channels x 64 pixels ----
        const int n = bid >> 8;
        const int pbase = (bid & 255) * 64;
        #pragma unroll
        for (int i = 0; i < 4; i++) {
            int idx = i * 256 + t;
            int c = idx >> 4, f4 = idx & 15;
            float4 v = *(const float4*)&x[((size_t)(n * CCH + c)) * HW + pbase + f4 * 4];
            float* d = &tile[c * 65 + f4 * 4];
            d[0] = v.x; d[1] = v.y; d[2] = v.z; d[3] = v.w;
        }
        __syncthreads();
        const int px = t >> 2, c4 = t & 3;
        float f[16];
        #pragma unroll
        for (int j = 0; j < 16; j++) f[j] = tile[(c4 * 16 + j) * 65 + px];
        unsigned int o8[8];
        #pragma unroll
        for (int i = 0; i < 8; i++) o8[i] = pack_f16(f[2 * i], f[2 * i + 1]);
        uint4* dst = (uint4*)&xt32[((size_t)(n * HW + pbase + px)) * 32 + c4 * 8];
        dst[0] = make_uint4(o8[0], o8[1], o8[2], o8[3]);
        dst[1] = make_uint4(o8[4], o8[5], o8[6], o8[7]);
    } else {
        // ---- each of 18 blocks: full maxabs (parallel, redundant) + 256 recs ----
        float m0 = 0.f, m1 = 0.f, m2 = 0.f, m3 = 0.f;
        for (int i = t; i < NW; i += 1024) {       // 36 iters, 4-way ILP
            m0 = fmaxf(m0, fabsf(w[i]));
            m1 = fmaxf(m1, fabsf(w[i + 256]));
            m2 = fmaxf(m2, fabsf(w[i + 512]));
            m3 = fmaxf(m3, fabsf(w[i + 768]));
        }
        float m = fmaxf(fmaxf(m0, m1), fmaxf(m2, m3));
        #pragma unroll
        for (int off = 32; off > 0; off >>= 1)
            m = fmaxf(m, __shfl_down(m, off));
        if ((t & 63) == 0) tile[t >> 6] = m;
        __syncthreads();
        m = fmaxf(fmaxf(tile[0], tile[1]), fmaxf(tile[2], tile[3]));
        const float scale = fmaxf(m, 1e-8f) / 127.f;
        const float inv_scale = 1.f / scale;

        const int rec = (bid - 2048) * 256 + t;    // 0..4607
        int nt  = rec / (KSTEPS * 64);
        int rem = rec - nt * (KSTEPS * 64);
        int s    = rem >> 6;
        int lane = rem & 63;
        int quad = lane >> 4, n16 = lane & 15;
        int o = nt * 16 + n16;
        unsigned int u[4];
        #pragma unroll
        for (int jj = 0; jj < 4; jj++) {
            float q[2];
            #pragma unroll
            for (int h = 0; h < 2; h++) {
                int k   = s * 32 + quad * 8 + 2 * jj + h;
                int c   = k & 63;
                int tap = k >> 6;
                float v  = w[(o * CCH + c) * KTAP + tap];
                float qq = rintf(v * inv_scale);          // RNE = jnp.round
                q[h] = fminf(fmaxf(qq, -128.f), 127.f) * scale;
            }
            u[jj] = pack_f16(q[0], q[1]);
        }
        bq[rec] = make_uint4(u[0], u[1], u[2], u[3]);
    }
}

// ---------- K2: deformable-sample + MFMA GEMM, 2 taps per barrier stage ----------
// Block = 64 px x 64 outs; wave w = 16-out slab (o = w*16+n16), all 64 px (4 m-tiles).
// 5 stages of {blend 2 taps -> LDS, prefetch next stage, barrier, 16 MFMA}.
__global__ __launch_bounds__(256) void deform_mfma(const unsigned short* __restrict__ xt,
                                                   const float* __restrict__ offset,
                                                   const uint4* __restrict__ bq,
                                                   float* __restrict__ out) {
    __shared__ _Float16 Abuf[2][2][4096];  // 32768 B: [stage-buf][tap-sub][64px*64ch]
    __shared__ unsigned int SC[576];       // packed clamped corners per (tap,px)
    __shared__ uint2 SW[576];              // packed f16 bilinear weights

    const int t    = threadIdx.x;
    const int wid  = t >> 6;
    const int lane = t & 63;
    const int quad = lane >> 4, n16 = lane & 15;
    const int bid  = blockIdx.x;
    const int n    = bid & 7;                 // image -> XCD swizzle
    const int px0  = (bid >> 3) * 64;
    const int pl   = t >> 2;                  // pixel within tile
    const int c4   = t & 3;                   // channel chunk id
    const int cb   = c4 * 16;                 // byte offset in 128B pixel row
    const int p7   = pl & 7;

    const char* xb = (const char*)(xt + (size_t)n * HW * CCH);
    const float* offn = offset + (size_t)n * 2 * KTAP * HW;

    // ---- setup: one task per (tap, pixel), cooperative across 256 threads ----
    for (int u = t; u < 576; u += 256) {
        const int tap = u >> 6, p = u & 63;
        const int ppx = px0 + p;
        const int ho = ppx >> 7, wo = ppx & 127;
        const int ky = tap / 3, kx = tap - 3 * ky;
        const float py  = (float)(ho - 1 + ky) + offn[(2 * tap) * HW + ppx];
        const float pxf = (float)(wo - 1 + kx) + offn[(2 * tap + 1) * HW + ppx];
        const float fy = floorf(py), fx = floorf(pxf);
        const int y0 = (int)fy, x0 = (int)fx;
        const float dy = py - fy, dx = pxf - fx;
        const int y1 = y0 + 1, x1 = x0 + 1;
        const bool vy0 = (y0 >= 0) && (y0 < HH);
        const bool vy1 = (y1 >= 0) && (y1 < HH);
        const bool vx0 = (x0 >= 0) && (x0 < WW);
        const bool vx1 = (x1 >= 0) && (x1 < WW);
        const int y0c = min(max(y0, 0), HH - 1);
        const int y1c = min(max(y1, 0), HH - 1);
        const int x0c = min(max(x0, 0), WW - 1);
        const int x1c = min(max(x1, 0), WW - 1);
        const float w00 = (1.f - dy) * (1.f - dx) * ((vy0 && vx0) ? 1.f : 0.f);
        const float w01 = (1.f - dy) * dx         * ((vy0 && vx1) ? 1.f : 0.f);
        const float w10 = dy * (1.f - dx)         * ((vy1 && vx0) ? 1.f : 0.f);
        const float w11 = dy * dx                 * ((vy1 && vx1) ? 1.f : 0.f);
        SC[u] = (unsigned)(y0c | (x0c << 7) | (y1c << 14) | (x1c << 21));
        SW[u] = make_uint2(pack_f16(w00, w01), pack_f16(w10, w11));
    }
    __syncthreads();           // setup visible

    f32x4 acc[4];
    #pragma unroll
    for (int mt = 0; mt < 4; mt++) acc[mt] = (f32x4){0.f, 0.f, 0.f, 0.f};

    uint4 rset[16];            // gathers for current stage (up to 2 taps)
    uint4 bset[2][4];          // double-buffered B frags (up to 4 ksteps/stage)

    auto gather8 = [&](int tap, uint4* r) {
        const unsigned int cc = SC[tap * 64 + pl];
        const int y0b = (int)(cc & 127) << 14;
        const int x0b = (int)((cc >> 7) & 127) << 7;
        const int y1b = (int)((cc >> 14) & 127) << 14;
        const int x1b = (int)(cc >> 21) << 7;
        const char* q00 = xb + (y0b | x0b) + cb;
        const char* q01 = xb + (y0b | x1b) + cb;
        const char* q10 = xb + (y1b | x0b) + cb;
        const char* q11 = xb + (y1b | x1b) + cb;
        r[0] = *(const uint4*)q00; r[1] = *(const uint4*)(q00 + 64);
        r[2] = *(const uint4*)q01; r[3] = *(const uint4*)(q01 + 64);
        r[4] = *(const uint4*)q10; r[5] = *(const uint4*)(q10 + 64);
        r[6] = *(const uint4*)q11; r[7] = *(const uint4*)(q11 + 64);
    };
    auto issue_stage = [&](int s) {
        gather8(2 * s, rset);
        if (s < 4) gather8(2 * s + 1, rset + 8);
        const int nk = (s < 4) ? 4 : 2;
        for (int k = 0; k < nk; k++)
            bset[s & 1][k] = bq[((size_t)wid * KSTEPS + 4 * s + k) * 64 + lane];
    };
    auto blend1 = [&](int tap, const uint4* r, _Float16* sub) {
        const uint2 ww = SW[tap * 64 + pl];
        const f16x2 wA = __builtin_bit_cast(f16x2, ww.x);   // w00, w01
        const f16x2 wB = __builtin_bit_cast(f16x2, ww.y);   // w10, w11
        f16x8 sa = as_f16x8(r[0]) * wA[0];
        sa += as_f16x8(r[2]) * wA[1];
        sa += as_f16x8(r[4]) * wB[0];
        sa += as_f16x8(r[6]) * wB[1];
        f16x8 sb = as_f16x8(r[1]) * wA[0];
        sb += as_f16x8(r[3]) * wA[1];
        sb += as_f16x8(r[5]) * wB[0];
        sb += as_f16x8(r[7]) * wB[1];
        *(f16x8*)&sub[pl * 64 + ((c4 ^ p7) * 8)]       = sa;
        *(f16x8*)&sub[pl * 64 + (((4 + c4) ^ p7) * 8)] = sb;
    };
    auto blend_stage = [&](int s) {
        blend1(2 * s, rset, Abuf[s & 1][0]);
        if (s < 4) blend1(2 * s + 1, rset + 8, Abuf[s & 1][1]);
    };
    auto mma_stage = [&](int s) {
        const int nk = (s < 4) ? 4 : 2;
        for (int ks = 0; ks < nk; ks++) {
            const _Float16* sub = Abuf[s & 1][ks >> 1];
            const f16x8 bf = __builtin_bit_cast(f16x8, bset[s & 1][ks]);
            #pragma unroll
            for (int mt = 0; mt < 4; mt++) {
                const int rr = mt * 16 + n16;
                const int slot = ((ks & 1) * 4 + quad) ^ (n16 & 7);
                const f16x8 a = *(const f16x8*)&sub[rr * 64 + slot * 8];
                acc[mt] = __builtin_amdgcn_mfma_f32_16x16x32_f16(a, bf, acc[mt], 0, 0, 0);
            }
        }
    };

    issue_stage(0);
    #pragma unroll
    for (int s = 0; s < 5; s++) {
        blend_stage(s);                  // consumes rset (waits only its own loads)
        if (s < 4) issue_stage(s + 1);   // prefetch flies across barrier + MFMAs
        __syncthreads();
        mma_stage(s);
    }

    // Epilogue: D col = n16 (out channel within slab), row = quad*4+reg (pixel)
    const int o = wid * 16 + n16;
    #pragma unroll
    for (int mt = 0; mt < 4; mt++) {
        float4 v = make_float4(acc[mt].x, acc[mt].y, acc[mt].z, acc[mt].w);
        float* dst = out + ((size_t)(n * CCH + o)) * HW + px0 + mt * 16 + quad * 4;
        *(float4*)dst = v;
    }
}

extern "C" void kernel_launch(void* const* d_in, const int* in_sizes, int n_in,
                              void* d_out, int out_size, void* d_ws, size_t ws_size,
                              hipStream_t stream) {
    const float* x      = (const float*)d_in[0];   // [8,64,128,128]
    const float* offset = (const float*)d_in[1];   // [8,18,128,128]
    const float* weight = (const float*)d_in[2];   // [64,64,3,3]
    float* out = (float*)d_out;                    // [8,64,128,128]

    unsigned char* ws = (unsigned char*)d_ws;
    uint4*        bq   = (uint4*)ws;                        // 73728 B
    unsigned int* xt32 = (unsigned int*)(ws + 131072);      // 8 MB (f16 NHWC)
    const unsigned short* xt = (const unsigned short*)xt32;

    prep_kernel<<<2048 + 18, 256, 0, stream>>>(x, weight, xt32, bq);
    deform_mfma<<<2048, 256, 0, stream>>>(xt, offset, bq, out);
}